// Round 12
// baseline (411.948 us; speedup 1.0000x reference)
//
#include <hip/hip_runtime.h>
#include <hip/hip_bf16.h>
#include <math.h>

#define S_LEN 2048
#define HID   2048
#define NH    32
#define NKV   8
#define HD    64
#define KVW   (NKV * HD)   // 512

typedef __attribute__((ext_vector_type(8))) short bf16x8;
typedef __attribute__((ext_vector_type(4))) float f32x4;
typedef unsigned short u16;

__device__ __forceinline__ u16 f2bf(float f) {
    return (u16)((__builtin_bit_cast(unsigned, f) + 0x8000u) >> 16);
}
__device__ __forceinline__ float bf2f(u16 v) {
    unsigned u = ((unsigned)v) << 16;
    return __builtin_bit_cast(float, u);
}
__device__ __forceinline__ unsigned pack2bf(float a, float b) {
    unsigned ua = __builtin_bit_cast(unsigned, a) + 0x8000u;
    unsigned ub = __builtin_bit_cast(unsigned, b) + 0x8000u;
    return (ua >> 16) | (ub & 0xFFFF0000u);
}
// async global->LDS, 16B/lane; LDS dest = wave-uniform base + lane*16
__device__ __forceinline__ void stage16(const u16* g, u16* lds_base) {
    __builtin_amdgcn_global_load_lds((const __attribute__((address_space(1))) void*)g,
                                     (__attribute__((address_space(3))) void*)lds_base, 16, 0, 0);
}

// ---------------------------------------------------------------------------
// Elementwise f32 -> bf16 (8 elems/thread).
// ---------------------------------------------------------------------------
__global__ __launch_bounds__(256) void cvt_bf16x8_kernel(const float* __restrict__ X,
                                                         u16* __restrict__ Y, int n8) {
    int i = blockIdx.x * 256 + threadIdx.x;
    if (i >= n8) return;
    const float4* p = (const float4*)(X + (size_t)i * 8);
    float4 a = p[0], b = p[1];
    uint4 o;
    o.x = pack2bf(a.x, a.y);
    o.y = pack2bf(a.z, a.w);
    o.z = pack2bf(b.x, b.y);
    o.w = pack2bf(b.z, b.w);
    *(uint4*)(Y + (size_t)i * 8) = o;
}

// ---------------------------------------------------------------------------
// Transpose+cvt all four weights in one launch. All sources have R=2048 rows.
// ---------------------------------------------------------------------------
__global__ __launch_bounds__(256) void transpose_cvt4(const float* __restrict__ Wq,
                                                      const float* __restrict__ Wk,
                                                      const float* __restrict__ Wv,
                                                      const float* __restrict__ Wo,
                                                      u16* __restrict__ WqkvT,
                                                      u16* __restrict__ WoT) {
    const float* X; u16* Y; int C;
    const int z = blockIdx.z;
    if (z == 0)      { X = Wq; Y = WqkvT;                        C = HID; }
    else if (z == 1) { X = Wo; Y = WoT;                          C = HID; }
    else if (z == 2) { X = Wk; Y = WqkvT + (size_t)2048 * HID;   C = KVW; }
    else             { X = Wv; Y = WqkvT + (size_t)2560 * HID;   C = KVW; }
    const int c0 = blockIdx.x * 32, r0 = blockIdx.y * 32;
    if (c0 >= C) return;
    __shared__ float T[32][33];
    const int tx = threadIdx.x & 31, ty = threadIdx.x >> 5;
#pragma unroll
    for (int i = 0; i < 4; i++)
        T[ty + 8 * i][tx] = X[(size_t)(r0 + ty + 8 * i) * C + c0 + tx];
    __syncthreads();
#pragma unroll
    for (int i = 0; i < 4; i++)
        Y[(size_t)(c0 + ty + 8 * i) * HID + r0 + tx] = f2bf(T[tx][ty + 8 * i]);
}

// ---------------------------------------------------------------------------
// bf16 MFMA GEMM, BM=BN=256, BK=32, 512 threads = 8 waves (2M x 4N), per-wave
// output 128x64, 32 NAMED f32x4 accumulators (spill-free per round 11:
// VGPR 116, WRITE_SIZE 12 MB; acc arrays are what spilled in rounds 7-9).
// NEW this round (single lever): 4-SLOT LDS RING + COUNTED vmcnt (round-6's
// harness-verified sync pattern, scaled): iter t stages tile t+3 (4 loads/
// thread), computes tile t (12 ds_read_b128 + 32 MFMA per wave), then waits
// vmcnt(8) (= tile t+1's 4 loads complete; t+2,t+3's 8 still in flight) +
// lgkmcnt(0) + s_barrier. NEVER a vmcnt(0) drain in the main loop -- tile
// t+1's loads were issued ~2 compute-tiles (~2000+ cyc) before they are
// waited on, covering HBM latency with zero cross-block TLP (1 block/CU).
// Invariant at top of iter t: tiles <= t resident; outstanding = {t+1,t+2}
// = 8 loads. Ring safety: slot (t+3)&3 was last read at iter t-1, separated
// by that iter's barrier. Tail peels waits 8 -> 4 -> 0.
// LDS: 4 slots x (A 16KB + B 16KB) = 128 KB. Fragment-order chunks (64
// lanes x 16B; chunk c = rows base+c*16+r, k = k0+qd*8) -> conflict-free
// ds_read_b128 (bank conflicts measured 0 across rounds 1-11).
// EPI=0: fp32 row-major C. EPI=1: fused QKV epilogue (Q / K+RoPE / V^T);
// per-wave 64 cols head-aligned -> RoPE pair (c,c+32) = acc cols n, n+2.
// ---------------------------------------------------------------------------
template <int EPI>
__global__ __launch_bounds__(512, 1) void gemm_bf16(const u16* __restrict__ A,
                                                    const u16* __restrict__ Bt,
                                                    float* __restrict__ C,
                                                    u16* __restrict__ Qh,
                                                    u16* __restrict__ Kh,
                                                    u16* __restrict__ Vt,
                                                    int K) {
    __shared__ u16 As[4][8192];   // 16 chunks x 512 u16 per slot (16 KB)
    __shared__ u16 Bs[4][8192];   // 16 chunks x 512 u16 per slot (16 KB)

    const int bm = blockIdx.y * 256, bn = blockIdx.x * 256;

    const int t = threadIdx.x;
    const int w = t >> 6, lane = t & 63;
    const int qd = lane >> 4, r = lane & 15;
    const int wm = w >> 2, wn = w & 3;      // 2M x 4N wave grid
    const bool kblk = (EPI == 1) && (bn >= 2048) && (bn < 2560);
    const int NT = K >> 5;                  // 64 K-tiles of BK=32

    // 32 named accumulators: aMN = output fragment (row-block M 0..7, col-block N 0..3)
    f32x4 a00={0,0,0,0},a01={0,0,0,0},a02={0,0,0,0},a03={0,0,0,0};
    f32x4 a10={0,0,0,0},a11={0,0,0,0},a12={0,0,0,0},a13={0,0,0,0};
    f32x4 a20={0,0,0,0},a21={0,0,0,0},a22={0,0,0,0},a23={0,0,0,0};
    f32x4 a30={0,0,0,0},a31={0,0,0,0},a32={0,0,0,0},a33={0,0,0,0};
    f32x4 a40={0,0,0,0},a41={0,0,0,0},a42={0,0,0,0},a43={0,0,0,0};
    f32x4 a50={0,0,0,0},a51={0,0,0,0},a52={0,0,0,0},a53={0,0,0,0};
    f32x4 a60={0,0,0,0},a61={0,0,0,0},a62={0,0,0,0},a63={0,0,0,0};
    f32x4 a70={0,0,0,0},a71={0,0,0,0},a72={0,0,0,0},a73={0,0,0,0};

// stage tile kt_ into slot (kt_)&3: wave w owns A chunks {2w,2w+1} and
// B chunks {2w,2w+1}; chunk c: rows base+c*16+r, k = kt_*32 + qd*8.
// 4 stage16 per thread per tile.
#define STAGE_TILE(kt_)                                                           \
    {                                                                             \
        const int s_ = (kt_) & 3;                                                 \
        const int k0_ = (kt_) * 32;                                               \
        _Pragma("unroll")                                                         \
        for (int l = 0; l < 2; l++) {                                             \
            const int chunk = w * 2 + l;                                          \
            const u16* ga = A + (size_t)(bm + chunk * 16 + r) * K + k0_ + qd * 8; \
            stage16(ga, &As[s_][chunk * 512]);                                    \
            const u16* gb = Bt + (size_t)(bn + chunk * 16 + r) * K + k0_ + qd * 8;\
            stage16(gb, &Bs[s_][chunk * 512]);                                    \
        }                                                                         \
    }

#define MFMA(a_, b_, c_) __builtin_amdgcn_mfma_f32_16x16x32_bf16(a_, b_, c_, 0, 0, 0)

// compute tile in slot s_: 12 named frag loads (conflict-free ds_read_b128)
// + 32 MFMA into the named acc grid.
#define COMPUTE_TILE(s_)                                                          \
    {                                                                             \
        const u16* Ab_ = &As[s_][0];                                              \
        const u16* Bb_ = &Bs[s_][0];                                              \
        bf16x8 af0 = *(const bf16x8*)&Ab_[(wm * 8 + 0) * 512 + lane * 8];         \
        bf16x8 af1 = *(const bf16x8*)&Ab_[(wm * 8 + 1) * 512 + lane * 8];         \
        bf16x8 af2 = *(const bf16x8*)&Ab_[(wm * 8 + 2) * 512 + lane * 8];         \
        bf16x8 af3 = *(const bf16x8*)&Ab_[(wm * 8 + 3) * 512 + lane * 8];         \
        bf16x8 af4 = *(const bf16x8*)&Ab_[(wm * 8 + 4) * 512 + lane * 8];         \
        bf16x8 af5 = *(const bf16x8*)&Ab_[(wm * 8 + 5) * 512 + lane * 8];         \
        bf16x8 af6 = *(const bf16x8*)&Ab_[(wm * 8 + 6) * 512 + lane * 8];         \
        bf16x8 af7 = *(const bf16x8*)&Ab_[(wm * 8 + 7) * 512 + lane * 8];         \
        bf16x8 bv0 = *(const bf16x8*)&Bb_[(wn * 4 + 0) * 512 + lane * 8];         \
        bf16x8 bv1 = *(const bf16x8*)&Bb_[(wn * 4 + 1) * 512 + lane * 8];         \
        bf16x8 bv2 = *(const bf16x8*)&Bb_[(wn * 4 + 2) * 512 + lane * 8];         \
        bf16x8 bv3 = *(const bf16x8*)&Bb_[(wn * 4 + 3) * 512 + lane * 8];         \
        a00 = MFMA(af0, bv0, a00); a01 = MFMA(af0, bv1, a01);                     \
        a02 = MFMA(af0, bv2, a02); a03 = MFMA(af0, bv3, a03);                     \
        a10 = MFMA(af1, bv0, a10); a11 = MFMA(af1, bv1, a11);                     \
        a12 = MFMA(af1, bv2, a12); a13 = MFMA(af1, bv3, a13);                     \
        a20 = MFMA(af2, bv0, a20); a21 = MFMA(af2, bv1, a21);                     \
        a22 = MFMA(af2, bv2, a22); a23 = MFMA(af2, bv3, a23);                     \
        a30 = MFMA(af3, bv0, a30); a31 = MFMA(af3, bv1, a31);                     \
        a32 = MFMA(af3, bv2, a32); a33 = MFMA(af3, bv3, a33);                     \
        a40 = MFMA(af4, bv0, a40); a41 = MFMA(af4, bv1, a41);                     \
        a42 = MFMA(af4, bv2, a42); a43 = MFMA(af4, bv3, a43);                     \
        a50 = MFMA(af5, bv0, a50); a51 = MFMA(af5, bv1, a51);                     \
        a52 = MFMA(af5, bv2, a52); a53 = MFMA(af5, bv3, a53);                     \
        a60 = MFMA(af6, bv0, a60); a61 = MFMA(af6, bv1, a61);                     \
        a62 = MFMA(af6, bv2, a62); a63 = MFMA(af6, bv3, a63);                     \
        a70 = MFMA(af7, bv0, a70); a71 = MFMA(af7, bv1, a71);                     \
        a72 = MFMA(af7, bv2, a72); a73 = MFMA(af7, bv3, a73);                     \
    }

    // prologue: tiles 0,1,2 in flight (12 loads); wait tile 0 (oldest 4), publish
    STAGE_TILE(0);
    STAGE_TILE(1);
    STAGE_TILE(2);
    asm volatile("s_waitcnt vmcnt(8)" ::: "memory");
    __builtin_amdgcn_s_barrier();

    for (int kt = 0; kt < NT - 3; ++kt) {
        STAGE_TILE(kt + 3);
        COMPUTE_TILE(kt & 3);
        asm volatile("s_waitcnt vmcnt(8) lgkmcnt(0)" ::: "memory");
        __builtin_amdgcn_s_barrier();
    }
    COMPUTE_TILE((NT - 3) & 3);
    asm volatile("s_waitcnt vmcnt(4) lgkmcnt(0)" ::: "memory");
    __builtin_amdgcn_s_barrier();
    COMPUTE_TILE((NT - 2) & 3);
    asm volatile("s_waitcnt vmcnt(0) lgkmcnt(0)" ::: "memory");
    __builtin_amdgcn_s_barrier();
    COMPUTE_TILE((NT - 1) & 3);
#undef STAGE_TILE
#undef COMPUTE_TILE
#undef MFMA

    // ---- epilogue (round-11 verified addressing, X-macro over named accs) ----
    const int row0 = bm + wm * 128;
    const int col0 = bn + wn * 64;

#define ACC_LIST(OP)                                                              \
    OP(0,0,a00) OP(0,1,a01) OP(0,2,a02) OP(0,3,a03)                               \
    OP(1,0,a10) OP(1,1,a11) OP(1,2,a12) OP(1,3,a13)                               \
    OP(2,0,a20) OP(2,1,a21) OP(2,2,a22) OP(2,3,a23)                               \
    OP(3,0,a30) OP(3,1,a31) OP(3,2,a32) OP(3,3,a33)                               \
    OP(4,0,a40) OP(4,1,a41) OP(4,2,a42) OP(4,3,a43)                               \
    OP(5,0,a50) OP(5,1,a51) OP(5,2,a52) OP(5,3,a53)                               \
    OP(6,0,a60) OP(6,1,a61) OP(6,2,a62) OP(6,3,a63)                               \
    OP(7,0,a70) OP(7,1,a71) OP(7,2,a72) OP(7,3,a73)

#define K_LIST(OP)                                                                \
    OP(0,0,a00,a02) OP(0,1,a01,a03) OP(1,0,a10,a12) OP(1,1,a11,a13)               \
    OP(2,0,a20,a22) OP(2,1,a21,a23) OP(3,0,a30,a32) OP(3,1,a31,a33)               \
    OP(4,0,a40,a42) OP(4,1,a41,a43) OP(5,0,a50,a52) OP(5,1,a51,a53)               \
    OP(6,0,a60,a62) OP(6,1,a61,a63) OP(7,0,a70,a72) OP(7,1,a71,a73)

    if (EPI == 0) {
#define ST_C(m_, n_, av)                                                          \
        _Pragma("unroll")                                                         \
        for (int reg = 0; reg < 4; reg++)                                         \
            C[(size_t)(row0 + m_ * 16 + qd * 4 + reg) * HID + col0 + n_ * 16 + r] = av[reg];
        ACC_LIST(ST_C)
#undef ST_C
    } else if (bn < 2048) {
#define ST_Q(m_, n_, av)                                                          \
        _Pragma("unroll")                                                         \
        for (int reg = 0; reg < 4; reg++)                                         \
            Qh[(size_t)(row0 + m_ * 16 + qd * 4 + reg) * HID + col0 + n_ * 16 + r] = f2bf(av[reg]);
        ACC_LIST(ST_Q)
#undef ST_Q
    } else if (kblk) {
        // K: fused RoPE. Wave covers one full head (64 head-aligned cols).
        // Pair (c, c+32): col-block n holds c = n*16+r, col-block n+2 holds c+32.
        const int hb = (bn - 2048) + wn * 64;             // head base in Kh row
#define ST_K(m_, n_, av, av2)                                                     \
        {                                                                         \
            const int c0 = n_ * 16 + r;                                           \
            const float inv = __expf(-(float)c0 * 0.2878231366242596f);           \
            _Pragma("unroll")                                                     \
            for (int reg = 0; reg < 4; reg++) {                                   \
                int srow = row0 + m_ * 16 + qd * 4 + reg;                         \
                float ang = (float)srow * inv;                                    \
                float cs = cosf(ang), sn = sinf(ang);                             \
                float k1 = av[reg], k2 = av2[reg];                                \
                size_t o = (size_t)srow * KVW + hb + c0;                          \
                Kh[o]      = f2bf(k1 * cs - k2 * sn);                             \
                Kh[o + 32] = f2bf(k2 * cs + k1 * sn);                             \
            }                                                                     \
        }
        K_LIST(ST_K)
#undef ST_K
    } else {
        // V: bf16 transposed Vt[512][2048]; 4 regs = 4 consecutive m -> 8B store
#define ST_V(m_, n_, av)                                                          \
        {                                                                         \
            int nrel = (bn - 2560) + wn * 64 + n_ * 16 + r;                       \
            int m0 = row0 + m_ * 16 + qd * 4;                                     \
            ushort4 v;                                                            \
            v.x = f2bf(av[0]); v.y = f2bf(av[1]);                                 \
            v.z = f2bf(av[2]); v.w = f2bf(av[3]);                                 \
            *(ushort4*)(Vt + (size_t)nrel * S_LEN + m0) = v;                      \
        }
        ACC_LIST(ST_V)
#undef ST_V
    }
#undef ACC_LIST
#undef K_LIST
}

// ---------------------------------------------------------------------------
// Flash attention, 512 threads (8 waves), 128 q-rows/block, 64-key tiles.
// (verified round-2 version: K double-buffered, V staged same-tile, two
// barriers per tile.) LDS 42 KB -> 3 blocks/CU.
// ---------------------------------------------------------------------------
__global__ __launch_bounds__(512, 6) void attn_mfma(const u16* __restrict__ Qh,
                                                    const u16* __restrict__ K,
                                                    const u16* __restrict__ Vt,
                                                    u16* __restrict__ O) {
    __shared__ u16 Kbuf[2][4096];     // 8 chunks x 512 u16
    __shared__ u16 Vbuf[4096];
    __shared__ u16 P_lds[8][16][72];

    const int w    = threadIdx.x >> 6;            // 0..7
    const int lane = threadIdx.x & 63;
    const int qd   = lane >> 4;
    const int r    = lane & 15;
    const int qb   = 15 - (int)blockIdx.x;        // heavy blocks first
    const int h    = blockIdx.y;
    const int kvh  = h >> 2;
    const int q0w  = qb * 128 + w * 16;           // wave's first q row

    // ---- Q: bf16 load, fp32 RoPE, scale, repack to A-frags ----
    const u16* qrow = Qh + (size_t)(q0w + r) * (NH * HD) + h * HD;
    bf16x8 qlo = *(const bf16x8*)(qrow + qd * 8);
    bf16x8 qhi = *(const bf16x8*)(qrow + 32 + qd * 8);
    float y1[8], y2[8];
    const float spos = (float)(q0w + r);
    const float LN1E4_OVER_32 = 0.2878231366242596f;
#pragma unroll
    for (int i = 0; i < 8; i++) {
        int jj = qd * 8 + i;
        float x1 = bf2f((u16)qlo[i]);
        float x2 = bf2f((u16)qhi[i]);
        float inv = __expf(-(float)jj * LN1E4_OVER_32);
        float ang = spos * inv;
        float c = cosf(ang), sn = sinf(ang);
        y1[i] = (x1 * c - x2 * sn) * 0.125f;
        y2[i] = (x2 * c + x1 * sn) * 0.125f;
    }
    bf16x8 qfrag[2];
    {
        union { unsigned u[4]; bf16x8 v; } a, b;
#pragma unroll
        for (int i = 0; i < 4; i++) {
            a.u[i] = pack2bf(y1[2 * i], y1[2 * i + 1]);
            b.u[i] = pack2bf(y2[2 * i], y2[2 * i + 1]);
        }
        qfrag[0] = a.v; qfrag[1] = b.v;
    }

    bf16x8 ones;
    {
        union { u16 s[8]; bf16x8 v; } u;
#pragma unroll
        for (int i = 0; i < 8; i++) u.s[i] = 0x3F80;
        ones = u.v;
    }

    f32x4 oacc[4];
    f32x4 lacc;
#pragma unroll
    for (int i = 0; i < 4; i++) { oacc[i][0]=0.f; oacc[i][1]=0.f; oacc[i][2]=0.f; oacc[i][3]=0.f; }
    lacc[0]=0.f; lacc[1]=0.f; lacc[2]=0.f; lacc[3]=0.f;

    const int ktmax = 2 * qb + 1;

    // one 16B stage per thread: wave w stages chunk w (nt = w>>1, cc = w&1)
#define STAGE_K(kt_, buf_)                                                        \
    {                                                                             \
        const u16* g = K + (size_t)((kt_) * 64 + (w >> 1) * 16 + r) * KVW         \
                         + kvh * HD + (w & 1) * 32 + qd * 8;                      \
        stage16(g, &Kbuf[buf_][w * 512]);                                         \
    }
#define STAGE_V(kt_)                                                              \
    {                                                                             \
        const u16* g = Vt + (size_t)(kvh * HD + (w >> 1) * 16 + r) * S_LEN        \
                          + (kt_) * 64 + (w & 1) * 32 + qd * 8;                   \
        stage16(g, &Vbuf[w * 512]);                                               \
    }

    STAGE_K(0, 0);
    __syncthreads();
    int cur = 0;

    for (int kt = 0; kt <= ktmax; kt++) {
        STAGE_V(kt);
        if (kt < ktmax) STAGE_K(kt + 1, cur ^ 1);

        // ---- S = Q K^T (16 q x 64 keys), conflict-free ds_read_b128 ----
        f32x4 s[4];
#pragma unroll
        for (int nt = 0; nt < 4; nt++) {
            bf16x8 kf0 = *(const bf16x8*)&Kbuf[cur][(nt * 2 + 0) * 512 + lane * 8];
            bf16x8 kf1 = *(const bf16x8*)&Kbuf[cur][(nt * 2 + 1) * 512 + lane * 8];
            f32x4 z; z[0]=0.f; z[1]=0.f; z[2]=0.f; z[3]=0.f;
            z = __builtin_amdgcn_mfma_f32_16x16x32_bf16(qfrag[0], kf0, z, 0, 0, 0);
            s[nt] = __builtin_amdgcn_mfma_f32_16x16x32_bf16(qfrag[1], kf1, z, 0, 0, 0);
        }

        // ---- causal mask ----
        if (kt * 64 + 63 > q0w) {
#pragma unroll
            for (int nt = 0; nt < 4; nt++) {
                int key = kt * 64 + nt * 16 + r;
#pragma unroll
                for (int reg = 0; reg < 4; reg++) {
                    int qg = q0w + qd * 4 + reg;
                    if (key > qg) s[nt][reg] = -1e30f;
                }
            }
        }

        // ---- p = exp(s) -> per-wave LDS (C-layout -> A-layout) ----
#pragma unroll
        for (int nt = 0; nt < 4; nt++)
#pragma unroll
            for (int reg = 0; reg < 4; reg++)
                P_lds[w][qd * 4 + reg][nt * 16 + r] = f2bf(__expf(s[nt][reg]));

        __syncthreads();   // V tile visible (P is per-wave, needs no barrier)

        // ---- O += P V ; l += P * ones ----
#pragma unroll
        for (int c = 0; c < 2; c++) {
            bf16x8 pf = *(const bf16x8*)&P_lds[w][r][c * 32 + qd * 8];
            lacc = __builtin_amdgcn_mfma_f32_16x16x32_bf16(pf, ones, lacc, 0, 0, 0);
#pragma unroll
            for (int ntd = 0; ntd < 4; ntd++) {
                bf16x8 vf = *(const bf16x8*)&Vbuf[(ntd * 2 + c) * 512 + lane * 8];
                oacc[ntd] = __builtin_amdgcn_mfma_f32_16x16x32_bf16(pf, vf, oacc[ntd], 0, 0, 0);
            }
        }

        __syncthreads();   // buf reads done before next iteration's staging
        cur ^= 1;
    }
#undef STAGE_K
#undef STAGE_V

    // ---- epilogue: O / l, store bf16 ----
    float rl[4];
#pragma unroll
    for (int reg = 0; reg < 4; reg++) rl[reg] = 1.f / lacc[reg];
#pragma unroll
    for (int ntd = 0; ntd < 4; ntd++)
#pragma unroll
        for (int reg = 0; reg < 4; reg++)
            O[(size_t)(q0w + qd * 4 + reg) * (NH * HD) + h * HD + ntd * 16 + r] =
                f2bf(oacc[ntd][reg] * rl[reg]);
}

// ---------------------------------------------------------------------------
// Launch: 5 dispatches.
// ---------------------------------------------------------------------------
extern "C" void kernel_launch(void* const* d_in, const int* in_sizes, int n_in,
                              void* d_out, int out_size, void* d_ws, size_t ws_size,
                              hipStream_t stream) {
    const float* hidden = (const float*)d_in[0];
    const float* Wq = (const float*)d_in[1];
    const float* Wk = (const float*)d_in[2];
    const float* Wv = (const float*)d_in[3];
    const float* Wo = (const float*)d_in[4];
    float* out = (float*)d_out;

    char* ws = (char*)d_ws;
    const size_t MB = 1024 * 1024;
    u16* Hh     = (u16*)(ws + 0 * MB);    // bf16 hidden          [2048][2048]   8 MB
    u16* WqkvT  = (u16*)(ws + 8 * MB);    // bf16 [Wq;Wk;Wv]^T    [3072][2048]  12 MB
    u16* WoT    = (u16*)(ws + 20 * MB);   // bf16 Wo^T            [2048][2048]   8 MB
    u16* Qh     = (u16*)(ws + 28 * MB);   // bf16 Q (no RoPE)     [2048][2048]   8 MB
    u16* Kh     = (u16*)(ws + 36 * MB);   // bf16 K (RoPE'd)      [2048][512]    2 MB
    u16* Vt     = (u16*)(ws + 38 * MB);   // bf16 V^T             [512][2048]    2 MB
    u16* Ob     = WqkvT;                  // attn out, reuses WqkvT (dead after QKV GEMM)

    cvt_bf16x8_kernel<<<(S_LEN * HID / 8 + 255) / 256, 256, 0, stream>>>(hidden, Hh, S_LEN * HID / 8);
    transpose_cvt4<<<dim3(HID / 32, HID / 32, 4), 256, 0, stream>>>(Wq, Wk, Wv, Wo, WqkvT, WoT);

    // fused QKV projection: N = 3072 (Q 2048 | K 512 | V 512), K-RoPE in epilogue
    gemm_bf16<1><<<dim3(3072 / 256, S_LEN / 256), 512, 0, stream>>>(Hh, WqkvT, nullptr, Qh, Kh, Vt, HID);

    attn_mfma<<<dim3(S_LEN / 128, NH), 512, 0, stream>>>(Qh, Kh, Vt, Ob);

    // output projection -> fp32 out
    gemm_bf16<0><<<dim3(HID / 256, S_LEN / 256), 512, 0, stream>>>(Ob, WoT, out, nullptr, nullptr, nullptr, HID);
}

// Round 13
// 325.745 us; speedup vs baseline: 1.2646x; 1.2646x over previous
//
#include <hip/hip_runtime.h>
#include <hip/hip_bf16.h>
#include <math.h>

#define S_LEN 2048
#define HID   2048
#define NH    32
#define NKV   8
#define HD    64
#define KVW   (NKV * HD)   // 512

typedef __attribute__((ext_vector_type(8))) short bf16x8;
typedef __attribute__((ext_vector_type(4))) float f32x4;
typedef unsigned short u16;

__device__ __forceinline__ u16 f2bf(float f) {
    return (u16)((__builtin_bit_cast(unsigned, f) + 0x8000u) >> 16);
}
__device__ __forceinline__ float bf2f(u16 v) {
    unsigned u = ((unsigned)v) << 16;
    return __builtin_bit_cast(float, u);
}
__device__ __forceinline__ unsigned pack2bf(float a, float b) {
    unsigned ua = __builtin_bit_cast(unsigned, a) + 0x8000u;
    unsigned ub = __builtin_bit_cast(unsigned, b) + 0x8000u;
    return (ua >> 16) | (ub & 0xFFFF0000u);
}
// async global->LDS, 16B/lane; LDS dest = wave-uniform base + lane*16
__device__ __forceinline__ void stage16(const u16* g, u16* lds_base) {
    __builtin_amdgcn_global_load_lds((const __attribute__((address_space(1))) void*)g,
                                     (__attribute__((address_space(3))) void*)lds_base, 16, 0, 0);
}

// ---------------------------------------------------------------------------
// Elementwise f32 -> bf16 (8 elems/thread).
// ---------------------------------------------------------------------------
__global__ __launch_bounds__(256) void cvt_bf16x8_kernel(const float* __restrict__ X,
                                                         u16* __restrict__ Y, int n8) {
    int i = blockIdx.x * 256 + threadIdx.x;
    if (i >= n8) return;
    const float4* p = (const float4*)(X + (size_t)i * 8);
    float4 a = p[0], b = p[1];
    uint4 o;
    o.x = pack2bf(a.x, a.y);
    o.y = pack2bf(a.z, a.w);
    o.z = pack2bf(b.x, b.y);
    o.w = pack2bf(b.z, b.w);
    *(uint4*)(Y + (size_t)i * 8) = o;
}

// ---------------------------------------------------------------------------
// Transpose+cvt all four weights in one launch. All sources have R=2048 rows.
// ---------------------------------------------------------------------------
__global__ __launch_bounds__(256) void transpose_cvt4(const float* __restrict__ Wq,
                                                      const float* __restrict__ Wk,
                                                      const float* __restrict__ Wv,
                                                      const float* __restrict__ Wo,
                                                      u16* __restrict__ WqkvT,
                                                      u16* __restrict__ WoT) {
    const float* X; u16* Y; int C;
    const int z = blockIdx.z;
    if (z == 0)      { X = Wq; Y = WqkvT;                        C = HID; }
    else if (z == 1) { X = Wo; Y = WoT;                          C = HID; }
    else if (z == 2) { X = Wk; Y = WqkvT + (size_t)2048 * HID;   C = KVW; }
    else             { X = Wv; Y = WqkvT + (size_t)2560 * HID;   C = KVW; }
    const int c0 = blockIdx.x * 32, r0 = blockIdx.y * 32;
    if (c0 >= C) return;
    __shared__ float T[32][33];
    const int tx = threadIdx.x & 31, ty = threadIdx.x >> 5;
#pragma unroll
    for (int i = 0; i < 4; i++)
        T[ty + 8 * i][tx] = X[(size_t)(r0 + ty + 8 * i) * C + c0 + tx];
    __syncthreads();
#pragma unroll
    for (int i = 0; i < 4; i++)
        Y[(size_t)(c0 + ty + 8 * i) * HID + r0 + tx] = f2bf(T[tx][ty + 8 * i]);
}

// ---------------------------------------------------------------------------
// bf16 MFMA GEMM, BM=64 BN=64 BK=64, 256 threads (2x2 waves, wave tile
// 32x32, acc[2][2]). This is the round-2-verified structure with BM halved:
// more blocks -> more resident waves (the empirically dominant lever:
// gemm time tracked waves/CU 6->12 across rounds 2/4/10 at ~1.7x per 2x).
// Grids: QKV (48,32)=1536 blocks ~5-6 blocks/CU; out-proj (32,32)=1024.
// LDS 32 KB dbuf -> 5 blocks/CU; __launch_bounds__(256,5) permits 5 under
// either 2nd-arg semantics (VGPR cap >=102, need ~60).
// LDS in FRAGMENT ORDER (chunk = 64 lanes x 16B) -> conflict-free
// ds_read_b128 (bank conflicts 0 across all rounds). A/B chunk c = tt*2+ss:
// rows base+tt*16+r, k = k0+ss*32+qd*8. DOUBLE-BUFFERED, one barrier per
// K-step; next-slab stages issued before compute (round-4 schedule).
// EPI=0: fp32 row-major C. EPI=1: fused QKV epilogue; K-blocks (1 head per
// 64-col block) use pair-swizzled B-tiles: wave wn reads tiles wn, wn+2 so
// frags j=0/1 hold within-head cols c and c+32 of the same lane (RoPE pair).
// ---------------------------------------------------------------------------
template <int EPI>
__global__ __launch_bounds__(256, 5) void gemm_bf16(const u16* __restrict__ A,
                                                    const u16* __restrict__ Bt,
                                                    float* __restrict__ C,
                                                    u16* __restrict__ Qh,
                                                    u16* __restrict__ Kh,
                                                    u16* __restrict__ Vt,
                                                    int K) {
    __shared__ u16 As[2][64 * 64];   // 8 chunks x 512 u16 = 8 KB per buf
    __shared__ u16 Bs[2][64 * 64];   // 8 chunks x 512 u16 = 8 KB per buf -> 32 KB

    const int t = threadIdx.x;
    const int w = t >> 6, lane = t & 63;
    const int qd = lane >> 4, r = lane & 15;
    const int wm = w >> 1, wn = w & 1;      // 2M x 2N wave grid, wave tile 32x32
    const int bm = blockIdx.y * 64, bn = blockIdx.x * 64;
    const bool kblk = (EPI == 1) && (bn >= 2048) && (bn < 2560);

    f32x4 acc[2][2];
#pragma unroll
    for (int i = 0; i < 2; i++)
#pragma unroll
        for (int j = 0; j < 2; j++) {
            acc[i][j][0] = 0.f; acc[i][j][1] = 0.f; acc[i][j][2] = 0.f; acc[i][j][3] = 0.f;
        }

    // stage one BK=64 slab: A 8 chunks + B 8 chunks over 4 waves
    // (wave w stages A chunks {w, w+4} and B chunks {w, w+4}; 4 stage16/thread)
    auto stageAB = [&](int k0, u16* dstA, u16* dstB) {
#pragma unroll
        for (int rd = 0; rd < 2; rd++) {
            int chunk = rd * 4 + w;
            int tt = chunk >> 1, ss = chunk & 1;
            const u16* ga = A + (size_t)(bm + tt * 16 + r) * K + k0 + ss * 32 + qd * 8;
            stage16(ga, dstA + chunk * 512);
            const u16* gb = Bt + (size_t)(bn + tt * 16 + r) * K + k0 + ss * 32 + qd * 8;
            stage16(gb, dstB + chunk * 512);
        }
    };

    stageAB(0, As[0], Bs[0]);
    __syncthreads();
    int cur = 0;

    for (int k0 = 0; k0 < K; k0 += 64) {
        if (k0 + 64 < K)
            stageAB(k0 + 64, As[cur ^ 1], Bs[cur ^ 1]);

#pragma unroll
        for (int ss = 0; ss < 2; ss++) {
            bf16x8 af[2], bfr[2];
#pragma unroll
            for (int i = 0; i < 2; i++)
                af[i] = *(const bf16x8*)&As[cur][((wm * 2 + i) * 2 + ss) * 512 + lane * 8];
#pragma unroll
            for (int j = 0; j < 2; j++) {
                int tile = kblk ? (wn + 2 * j) : (wn * 2 + j);
                bfr[j] = *(const bf16x8*)&Bs[cur][(tile * 2 + ss) * 512 + lane * 8];
            }
#pragma unroll
            for (int i = 0; i < 2; i++)
#pragma unroll
                for (int j = 0; j < 2; j++)
                    acc[i][j] = __builtin_amdgcn_mfma_f32_16x16x32_bf16(af[i], bfr[j], acc[i][j], 0, 0, 0);
        }

        __syncthreads();   // all reads of cur done; next-slab loads drained
        cur ^= 1;
    }

    const int row0 = bm + wm * 32;
    if (EPI == 0) {
#pragma unroll
        for (int i = 0; i < 2; i++)
#pragma unroll
            for (int j = 0; j < 2; j++)
#pragma unroll
                for (int reg = 0; reg < 4; reg++)
                    C[(size_t)(row0 + i * 16 + qd * 4 + reg) * HID + bn + wn * 32 + j * 16 + r] =
                        acc[i][j][reg];
    } else if (bn < 2048) {
        // Q: bf16 row-major [2048][2048]
#pragma unroll
        for (int i = 0; i < 2; i++)
#pragma unroll
            for (int j = 0; j < 2; j++)
#pragma unroll
                for (int reg = 0; reg < 4; reg++)
                    Qh[(size_t)(row0 + i * 16 + qd * 4 + reg) * HID + bn + wn * 32 + j * 16 + r] =
                        f2bf(acc[i][j][reg]);
    } else if (kblk) {
        // K: fused RoPE. frag j=0 -> within-head col c0, j=1 -> c0+32 (pair-swizzle)
        const int c0 = wn * 16 + r;                       // within-head col 0..31
        const int hb = bn - 2048;                          // head base (1 head/block)
        const float inv = __expf(-(float)c0 * 0.2878231366242596f);  // 10000^(-c0/32)
#pragma unroll
        for (int i = 0; i < 2; i++)
#pragma unroll
            for (int reg = 0; reg < 4; reg++) {
                int srow = row0 + i * 16 + qd * 4 + reg;
                float ang = (float)srow * inv;
                float cs = cosf(ang), sn = sinf(ang);
                float k1 = acc[i][0][reg], k2 = acc[i][1][reg];
                size_t o = (size_t)srow * KVW + hb + c0;
                Kh[o]      = f2bf(k1 * cs - k2 * sn);
                Kh[o + 32] = f2bf(k2 * cs + k1 * sn);
            }
    } else {
        // V: bf16 transposed Vt[512][2048]; 4 regs = 4 consecutive m -> 8B store
#pragma unroll
        for (int i = 0; i < 2; i++)
#pragma unroll
            for (int j = 0; j < 2; j++) {
                int nrel = (bn - 2560) + wn * 32 + j * 16 + r;
                int m0 = row0 + i * 16 + qd * 4;
                ushort4 v;
                v.x = f2bf(acc[i][j][0]); v.y = f2bf(acc[i][j][1]);
                v.z = f2bf(acc[i][j][2]); v.w = f2bf(acc[i][j][3]);
                *(ushort4*)(Vt + (size_t)nrel * S_LEN + m0) = v;
            }
    }
}

// ---------------------------------------------------------------------------
// Flash attention, 512 threads (8 waves), 128 q-rows/block, 64-key tiles.
// (verified round-2 version: K double-buffered, V staged same-tile, two
// barriers per tile.) LDS 42 KB -> 3 blocks/CU.
// ---------------------------------------------------------------------------
__global__ __launch_bounds__(512, 6) void attn_mfma(const u16* __restrict__ Qh,
                                                    const u16* __restrict__ K,
                                                    const u16* __restrict__ Vt,
                                                    u16* __restrict__ O) {
    __shared__ u16 Kbuf[2][4096];     // 8 chunks x 512 u16
    __shared__ u16 Vbuf[4096];
    __shared__ u16 P_lds[8][16][72];

    const int w    = threadIdx.x >> 6;            // 0..7
    const int lane = threadIdx.x & 63;
    const int qd   = lane >> 4;
    const int r    = lane & 15;
    const int qb   = 15 - (int)blockIdx.x;        // heavy blocks first
    const int h    = blockIdx.y;
    const int kvh  = h >> 2;
    const int q0w  = qb * 128 + w * 16;           // wave's first q row

    // ---- Q: bf16 load, fp32 RoPE, scale, repack to A-frags ----
    const u16* qrow = Qh + (size_t)(q0w + r) * (NH * HD) + h * HD;
    bf16x8 qlo = *(const bf16x8*)(qrow + qd * 8);
    bf16x8 qhi = *(const bf16x8*)(qrow + 32 + qd * 8);
    float y1[8], y2[8];
    const float spos = (float)(q0w + r);
    const float LN1E4_OVER_32 = 0.2878231366242596f;
#pragma unroll
    for (int i = 0; i < 8; i++) {
        int jj = qd * 8 + i;
        float x1 = bf2f((u16)qlo[i]);
        float x2 = bf2f((u16)qhi[i]);
        float inv = __expf(-(float)jj * LN1E4_OVER_32);
        float ang = spos * inv;
        float c = cosf(ang), sn = sinf(ang);
        y1[i] = (x1 * c - x2 * sn) * 0.125f;
        y2[i] = (x2 * c + x1 * sn) * 0.125f;
    }
    bf16x8 qfrag[2];
    {
        union { unsigned u[4]; bf16x8 v; } a, b;
#pragma unroll
        for (int i = 0; i < 4; i++) {
            a.u[i] = pack2bf(y1[2 * i], y1[2 * i + 1]);
            b.u[i] = pack2bf(y2[2 * i], y2[2 * i + 1]);
        }
        qfrag[0] = a.v; qfrag[1] = b.v;
    }

    bf16x8 ones;
    {
        union { u16 s[8]; bf16x8 v; } u;
#pragma unroll
        for (int i = 0; i < 8; i++) u.s[i] = 0x3F80;
        ones = u.v;
    }

    f32x4 oacc[4];
    f32x4 lacc;
#pragma unroll
    for (int i = 0; i < 4; i++) { oacc[i][0]=0.f; oacc[i][1]=0.f; oacc[i][2]=0.f; oacc[i][3]=0.f; }
    lacc[0]=0.f; lacc[1]=0.f; lacc[2]=0.f; lacc[3]=0.f;

    const int ktmax = 2 * qb + 1;

    // one 16B stage per thread: wave w stages chunk w (nt = w>>1, cc = w&1)
#define STAGE_K(kt_, buf_)                                                        \
    {                                                                             \
        const u16* g = K + (size_t)((kt_) * 64 + (w >> 1) * 16 + r) * KVW         \
                         + kvh * HD + (w & 1) * 32 + qd * 8;                      \
        stage16(g, &Kbuf[buf_][w * 512]);                                         \
    }
#define STAGE_V(kt_)                                                              \
    {                                                                             \
        const u16* g = Vt + (size_t)(kvh * HD + (w >> 1) * 16 + r) * S_LEN        \
                          + (kt_) * 64 + (w & 1) * 32 + qd * 8;                   \
        stage16(g, &Vbuf[w * 512]);                                               \
    }

    STAGE_K(0, 0);
    __syncthreads();
    int cur = 0;

    for (int kt = 0; kt <= ktmax; kt++) {
        STAGE_V(kt);
        if (kt < ktmax) STAGE_K(kt + 1, cur ^ 1);

        // ---- S = Q K^T (16 q x 64 keys), conflict-free ds_read_b128 ----
        f32x4 s[4];
#pragma unroll
        for (int nt = 0; nt < 4; nt++) {
            bf16x8 kf0 = *(const bf16x8*)&Kbuf[cur][(nt * 2 + 0) * 512 + lane * 8];
            bf16x8 kf1 = *(const bf16x8*)&Kbuf[cur][(nt * 2 + 1) * 512 + lane * 8];
            f32x4 z; z[0]=0.f; z[1]=0.f; z[2]=0.f; z[3]=0.f;
            z = __builtin_amdgcn_mfma_f32_16x16x32_bf16(qfrag[0], kf0, z, 0, 0, 0);
            s[nt] = __builtin_amdgcn_mfma_f32_16x16x32_bf16(qfrag[1], kf1, z, 0, 0, 0);
        }

        // ---- causal mask ----
        if (kt * 64 + 63 > q0w) {
#pragma unroll
            for (int nt = 0; nt < 4; nt++) {
                int key = kt * 64 + nt * 16 + r;
#pragma unroll
                for (int reg = 0; reg < 4; reg++) {
                    int qg = q0w + qd * 4 + reg;
                    if (key > qg) s[nt][reg] = -1e30f;
                }
            }
        }

        // ---- p = exp(s) -> per-wave LDS (C-layout -> A-layout) ----
#pragma unroll
        for (int nt = 0; nt < 4; nt++)
#pragma unroll
            for (int reg = 0; reg < 4; reg++)
                P_lds[w][qd * 4 + reg][nt * 16 + r] = f2bf(__expf(s[nt][reg]));

        __syncthreads();   // V tile visible (P is per-wave, needs no barrier)

        // ---- O += P V ; l += P * ones ----
#pragma unroll
        for (int c = 0; c < 2; c++) {
            bf16x8 pf = *(const bf16x8*)&P_lds[w][r][c * 32 + qd * 8];
            lacc = __builtin_amdgcn_mfma_f32_16x16x32_bf16(pf, ones, lacc, 0, 0, 0);
#pragma unroll
            for (int ntd = 0; ntd < 4; ntd++) {
                bf16x8 vf = *(const bf16x8*)&Vbuf[(ntd * 2 + c) * 512 + lane * 8];
                oacc[ntd] = __builtin_amdgcn_mfma_f32_16x16x32_bf16(pf, vf, oacc[ntd], 0, 0, 0);
            }
        }

        __syncthreads();   // buf reads done before next iteration's staging
        cur ^= 1;
    }
#undef STAGE_K
#undef STAGE_V

    // ---- epilogue: O / l, store bf16 ----
    float rl[4];
#pragma unroll
    for (int reg = 0; reg < 4; reg++) rl[reg] = 1.f / lacc[reg];
#pragma unroll
    for (int ntd = 0; ntd < 4; ntd++)
#pragma unroll
        for (int reg = 0; reg < 4; reg++)
            O[(size_t)(q0w + qd * 4 + reg) * (NH * HD) + h * HD + ntd * 16 + r] =
                f2bf(oacc[ntd][reg] * rl[reg]);
}

// ---------------------------------------------------------------------------
// Launch: 5 dispatches.
// ---------------------------------------------------------------------------
extern "C" void kernel_launch(void* const* d_in, const int* in_sizes, int n_in,
                              void* d_out, int out_size, void* d_ws, size_t ws_size,
                              hipStream_t stream) {
    const float* hidden = (const float*)d_in[0];
    const float* Wq = (const float*)d_in[1];
    const float* Wk = (const float*)d_in[2];
    const float* Wv = (const float*)d_in[3];
    const float* Wo = (const float*)d_in[4];
    float* out = (float*)d_out;

    char* ws = (char*)d_ws;
    const size_t MB = 1024 * 1024;
    u16* Hh     = (u16*)(ws + 0 * MB);    // bf16 hidden          [2048][2048]   8 MB
    u16* WqkvT  = (u16*)(ws + 8 * MB);    // bf16 [Wq;Wk;Wv]^T    [3072][2048]  12 MB
    u16* WoT    = (u16*)(ws + 20 * MB);   // bf16 Wo^T            [2048][2048]   8 MB
    u16* Qh     = (u16*)(ws + 28 * MB);   // bf16 Q (no RoPE)     [2048][2048]   8 MB
    u16* Kh     = (u16*)(ws + 36 * MB);   // bf16 K (RoPE'd)      [2048][512]    2 MB
    u16* Vt     = (u16*)(ws + 38 * MB);   // bf16 V^T             [512][2048]    2 MB
    u16* Ob     = WqkvT;                  // attn out, reuses WqkvT (dead after QKV GEMM)

    cvt_bf16x8_kernel<<<(S_LEN * HID / 8 + 255) / 256, 256, 0, stream>>>(hidden, Hh, S_LEN * HID / 8);
    transpose_cvt4<<<dim3(HID / 32, HID / 32, 4), 256, 0, stream>>>(Wq, Wk, Wv, Wo, WqkvT, WoT);

    // fused QKV projection: N = 3072 (Q 2048 | K 512 | V 512), K-RoPE in epilogue
    gemm_bf16<1><<<dim3(3072 / 64, S_LEN / 64), 256, 0, stream>>>(Hh, WqkvT, nullptr, Qh, Kh, Vt, HID);

    attn_mfma<<<dim3(S_LEN / 128, NH), 512, 0, stream>>>(Qh, Kh, Vt, Ob);

    // output projection -> fp32 out
    gemm_bf16<0><<<dim3(HID / 64, S_LEN / 64), 256, 0, stream>>>(Ob, WoT, out, nullptr, nullptr, nullptr, HID);
}